// Round 8
// baseline (63.642 us; speedup 1.0000x reference)
//
#include <hip/hip_runtime.h>
#include <hip/hip_bf16.h>
#include <stdint.h>

#define N_TOT 8192
#define BSZ   4096
#define NCH   16                     // 8192/512 column groups
#define SCALE2 28.853900817779268f   // 20 * log2(e): base-2 domain
#define SKIP_THR 125.0f              // exp2 window: skipped terms are below ulp(sum)

typedef _Float16 f16x8 __attribute__((ext_vector_type(8)));
typedef float f32x4 __attribute__((ext_vector_type(4)));

// ---------------- prep: f32 -> fp16 H; block 512 = label hist + byte labels ----------------
__global__ __launch_bounds__(256) void prep_kernel(
    const float* __restrict__ feat, const int* __restrict__ labels,
    _Float16* __restrict__ H, unsigned char* __restrict__ lab8, int* __restrict__ cnt) {
  if (blockIdx.x == 512) {
    __shared__ int h[128];
    if (threadIdx.x < 128) h[threadIdx.x] = 0;
    __syncthreads();
    for (int i = threadIdx.x; i < BSZ; i += 256) atomicAdd(&h[labels[i] & 127], 1);
    __syncthreads();
    if (threadIdx.x < 128) cnt[threadIdx.x] = h[threadIdx.x];
    for (int i = threadIdx.x; i < N_TOT; i += 256)
      lab8[i] = (unsigned char)labels[i & (BSZ - 1)];
    return;
  }
  int idx = blockIdx.x * 256 + threadIdx.x;   // 131072 threads, 8 halves each
  int r = idx >> 4, c8 = (idx & 15) << 3;
  int b = r & (BSZ - 1), v = r >> 12;         // cf row r = features[b, v, :]
  const float* src = feat + ((size_t)((b << 1) + v) << 7) + c8;
  float4 x0 = *(const float4*)src;
  float4 x1 = *(const float4*)(src + 4);
  float xs[8] = {x0.x, x0.y, x0.z, x0.w, x1.x, x1.y, x1.z, x1.w};
  f16x8 hv;
#pragma unroll
  for (int j = 0; j < 8; ++j) hv[j] = (_Float16)xs[j];
  *(f16x8*)(H + (size_t)r * 128 + c8) = hv;
}

// ---------------- LDS-free strip GEMM: 1 wave = 64 rows x 512 cols, K=128 ----------------
// All operands global->VGPR (B slab L2-resident, pinned per-XCD). No barriers, no LDS.
// Transposed MFMA: acc[m][ni][r] = C[row = strip*64+m*16+lr16][col = cg*512+t*64+ni*16+lq*4+r]
// A pre-scaled by SCALE2; online per-row (max, exp2-sum) with wave-uniform exp-skip.
__global__ __launch_bounds__(64, 2) void gemm_kernel(
    const _Float16* __restrict__ H, const int* __restrict__ labels,
    const unsigned char* __restrict__ lab8,
    float* __restrict__ pM, float* __restrict__ pS) {
  int orig = blockIdx.x;                 // 2048 blocks
  int xcd = orig & 7, j = orig >> 3;     // round-robin XCD dispatch assumption (perf-only)
  int cg = xcd * 2 + (j & 1);            // [0,16): col-group pinned to XCD -> B slab in its L2
  int strip = j >> 1;                    // [0,128)

  int lane = threadIdx.x & 63;
  int lq = lane >> 4, lr16 = lane & 15;

  const uint32_t rowbase = (uint32_t)strip * 64;
  const uint32_t colbase = (uint32_t)cg * 512;

  // row labels (4 m-groups)
  int lrw[4];
#pragma unroll
  for (int m = 0; m < 4; ++m)
    lrw[m] = labels[(rowbase + m * 16 + lr16) & (BSZ - 1)];

  // ---- A fragments: 16 dwordx4 loads, fragment layout, pre-scaled ----
  f16x8 Areg[4][4];
#pragma unroll
  for (int m = 0; m < 4; ++m)
#pragma unroll
    for (int kb = 0; kb < 4; ++kb)
      Areg[m][kb] = *(const f16x8*)(H + (size_t)(rowbase + m * 16 + lr16) * 128 + kb * 32 + lq * 8);
#pragma unroll
  for (int m = 0; m < 4; ++m)
#pragma unroll
    for (int kb = 0; kb < 4; ++kb)
      Areg[m][kb] = Areg[m][kb] * (_Float16)SCALE2;

  f32x4 acc[4][4];
#pragma unroll
  for (int m = 0; m < 4; ++m)
#pragma unroll
    for (int ni = 0; ni < 4; ++ni) acc[m][ni] = f32x4{0.f, 0.f, 0.f, 0.f};
  float mxv[4] = {-3.0e38f, -3.0e38f, -3.0e38f, -3.0e38f};
  float sv[4] = {0.0f, 0.0f, 0.0f, 0.0f};

  // ---- preload tile 0's B fragments (16 dwordx4) ----
  f16x8 B[4][4];
#pragma unroll
  for (int kb = 0; kb < 4; ++kb)
#pragma unroll
    for (int ni = 0; ni < 4; ++ni)
      B[kb][ni] = *(const f16x8*)(H + (size_t)(colbase + ni * 16 + lr16) * 128 + kb * 32 + lq * 8);

#pragma unroll 1
  for (int t = 0; t < 8; ++t) {
    // col labels for this tile (L1/L2-resident 8KB array)
    uint32_t labw[4];
#pragma unroll
    for (int ni = 0; ni < 4; ++ni)
      labw[ni] = *(const uint32_t*)(lab8 + colbase + t * 64 + ni * 16 + lq * 4);

    // ---- MFMA: 64 ops, K=128 ----
    __builtin_amdgcn_s_setprio(1);
#pragma unroll
    for (int kb = 0; kb < 4; ++kb)
#pragma unroll
      for (int m = 0; m < 4; ++m)
#pragma unroll
        for (int ni = 0; ni < 4; ++ni)
          acc[m][ni] = __builtin_amdgcn_mfma_f32_16x16x32_f16(B[kb][ni], Areg[m][kb], acc[m][ni], 0, 0, 0);
    __builtin_amdgcn_s_setprio(0);

    // ---- prefetch next tile's B (lands under the epilogue below) ----
    {
      uint32_t ntc = colbase + (uint32_t)(((t + 1) & 7) * 64);
#pragma unroll
      for (int kb = 0; kb < 4; ++kb)
#pragma unroll
        for (int ni = 0; ni < 4; ++ni)
          B[kb][ni] = *(const f16x8*)(H + (size_t)(ntc + ni * 16 + lr16) * 128 + kb * 32 + lq * 8);
    }

    // ---- epilogue: mask in-place, per-row online (max, exp2-sum), wave-uniform skip ----
#pragma unroll
    for (int m = 0; m < 4; ++m) {
#pragma unroll
      for (int ni = 0; ni < 4; ++ni)
#pragma unroll
        for (int r = 0; r < 4; ++r) {
          int lc = (labw[ni] >> (8 * r)) & 255;
          acc[m][ni][r] = (lrw[m] != lc) ? acc[m][ni][r] : 0.0f;
        }
      float a0 = fmaxf(fmaxf(acc[m][0][0], acc[m][0][1]), fmaxf(acc[m][0][2], acc[m][0][3]));
      float a1 = fmaxf(fmaxf(acc[m][1][0], acc[m][1][1]), fmaxf(acc[m][1][2], acc[m][1][3]));
      float a2 = fmaxf(fmaxf(acc[m][2][0], acc[m][2][1]), fmaxf(acc[m][2][2], acc[m][2][3]));
      float a3 = fmaxf(fmaxf(acc[m][3][0], acc[m][3][1]), fmaxf(acc[m][3][2], acc[m][3][3]));
      float bm = fmaxf(fmaxf(a0, a1), fmaxf(a2, a3));
      bm = fmaxf(bm, __shfl_xor(bm, 16, 64));
      bm = fmaxf(bm, __shfl_xor(bm, 32, 64));
      // skipped terms <= 2^-125 relative to sv (>=1): bit-exact to include-or-not
      if (__any(bm > mxv[m] - SKIP_THR)) {
        float nm = fmaxf(mxv[m], bm);
        float s0 = 0.f, s1 = 0.f;
#pragma unroll
        for (int ni = 0; ni < 2; ++ni)
#pragma unroll
          for (int r = 0; r < 4; ++r) {
            s0 += exp2f(acc[m][ni][r] - nm);
            s1 += exp2f(acc[m][2 + ni][r] - nm);
          }
        float s = s0 + s1;
        s += __shfl_xor(s, 16, 64);
        s += __shfl_xor(s, 32, 64);
        sv[m] = sv[m] * exp2f(mxv[m] - nm) + s;
        mxv[m] = nm;
      }
#pragma unroll
      for (int ni = 0; ni < 4; ++ni) acc[m][ni] = f32x4{0.f, 0.f, 0.f, 0.f};
    }
  }

  // ---- write per-(row, cg) partials: lanes 0-15 hold the quad-reduced values ----
  if (lane < 16) {
#pragma unroll
    for (int m = 0; m < 4; ++m) {
      pM[(size_t)cg * N_TOT + rowbase + m * 16 + lane] = mxv[m];
      pS[(size_t)cg * N_TOT + rowbase + m * 16 + lane] = sv[m];
    }
  }
}

// ---------------- combine 16 chunk-partials per row, partial-sum S per block ----------------
__global__ __launch_bounds__(256) void rowred_kernel(const float* __restrict__ pM,
                                                     const float* __restrict__ pS,
                                                     float* __restrict__ blockS) {
  int row = blockIdx.x * 256 + threadIdx.x;   // 32 blocks x 256 = 8192 rows
  float M = -3.0e38f;
#pragma unroll
  for (int c = 0; c < NCH; ++c) M = fmaxf(M, pM[(size_t)c * N_TOT + row]);
  float s = 0.0f;
#pragma unroll
  for (int c = 0; c < NCH; ++c)
    s += pS[(size_t)c * N_TOT + row] * exp2f(pM[(size_t)c * N_TOT + row] - M);
  __shared__ float red[256];
  red[threadIdx.x] = s;
  __syncthreads();
  for (int st = 128; st > 0; st >>= 1) {
    if (threadIdx.x < st) red[threadIdx.x] += red[threadIdx.x + st];
    __syncthreads();
  }
  if (threadIdx.x == 0) blockS[blockIdx.x] = red[0];
}

// ---------------- final scalar: S, N, validity -> loss ----------------
__global__ void final_kernel(const float* __restrict__ blockS, const int* __restrict__ cnt,
                             float* __restrict__ out) {
  int lane = threadIdx.x;              // 1 wave
  float s = (lane < 32) ? blockS[lane] : 0.0f;
#pragma unroll
  for (int off = 1; off < 64; off <<= 1) s += __shfl_xor(s, off, 64);
  if (lane == 0) {
    double Stot = (double)s;
    long long sumsq = 0;
    int nval = 0;
    for (int c = 0; c < 128; ++c) {
      long long cc = cnt[c];
      sumsq += cc * cc;
      if (cc > 0 && cc < BSZ) nval += 2 * (int)cc;   // valid rows iff not all labels equal
    }
    double Nd = (double)N_TOT * (double)N_TOT - 4.0 * (double)sumsq;
    float loss;
    if (Nd <= 0.0 || nval == 0) {
      loss = logf(1e-6f);              // all_zero branch: xv stays 0 -> log(eps)
    } else {
      float x = (float)(Stot / Nd);
      loss = ((float)nval * logf(x + 1e-6f) +
              (float)(N_TOT - nval) * logf(1e-6f)) / (float)N_TOT;
    }
    out[0] = loss;
  }
}

extern "C" void kernel_launch(void* const* d_in, const int* in_sizes, int n_in,
                              void* d_out, int out_size, void* d_ws, size_t ws_size,
                              hipStream_t stream) {
  const float* feat = (const float*)d_in[0];
  const int* labels = (const int*)d_in[1];
  float* out = (float*)d_out;

  char* ws = (char*)d_ws;
  _Float16* H         = (_Float16*)(ws);                 // 8192*128*2 = 2,097,152
  unsigned char* lab8 = (unsigned char*)(ws + 2097152);  // 8,192
  float* pM           = (float*)(ws + 2105344);          // 16*8192*4 = 524,288
  float* pS           = (float*)(ws + 2629632);          // 524,288
  int* cnt            = (int*)(ws + 3153920);            // 512
  float* blockS       = (float*)(ws + 3154432);          // 128

  prep_kernel<<<513, 256, 0, stream>>>(feat, labels, H, lab8, cnt);
  gemm_kernel<<<2048, 64, 0, stream>>>(H, labels, lab8, pM, pS);
  rowred_kernel<<<32, 256, 0, stream>>>(pM, pS, blockS);
  final_kernel<<<1, 64, 0, stream>>>(blockS, cnt, out);
}

// Round 10
// 50.876 us; speedup vs baseline: 1.2509x; 1.2509x over previous
//
#include <hip/hip_runtime.h>
#include <hip/hip_bf16.h>
#include <stdint.h>

#define N_TOT 8192
#define BSZ   4096
#define NCH   32                     // 8192/256 column groups
#define SCALE2 28.853900817779268f   // 20 * log2(e): base-2 domain
#define SKIP_THR 40.0f               // dropped tiles contribute < 2^-40 relative

typedef _Float16 f16x8 __attribute__((ext_vector_type(8)));
typedef float f32x4 __attribute__((ext_vector_type(4)));

extern "C" __device__ float __ocml_native_exp2_f32(float);   // -> v_exp_f32
#define EXP2(x) __ocml_native_exp2_f32(x)

// ---------------- prep: f32 -> fp16 in FRAGMENT-TILE layout ----------------
// H2 byte addr = rowblk*4096 + k8*256 + (r&15)*16  (rowblk=r>>4, k8=k/8)
// => every MFMA fragment load (16 rows x 8 k's) is a contiguous 1KB wave load.
__global__ __launch_bounds__(256) void prep_kernel(
    const float* __restrict__ feat, const int* __restrict__ labels,
    _Float16* __restrict__ H2, unsigned char* __restrict__ lab8, int* __restrict__ cnt) {
  if (blockIdx.x == 512) {   // label histogram + byte labels
    __shared__ int h[128];
    if (threadIdx.x < 128) h[threadIdx.x] = 0;
    __syncthreads();
    for (int i = threadIdx.x; i < BSZ; i += 256) atomicAdd(&h[labels[i] & 127], 1);
    __syncthreads();
    if (threadIdx.x < 128) cnt[threadIdx.x] = h[threadIdx.x];
    for (int i = threadIdx.x; i < N_TOT; i += 256)
      lab8[i] = (unsigned char)labels[i & (BSZ - 1)];
    return;
  }
  int idx = blockIdx.x * 256 + threadIdx.x;   // 131072
  int rowblk = idx >> 8, inner = idx & 255;
  int k8 = inner >> 4, rlo = inner & 15;
  int r = rowblk * 16 + rlo;
  int b = r & (BSZ - 1), v = r >> 12;         // cf row r = features[b, v, :]
  const float* src = feat + ((size_t)((b << 1) + v) << 7) + k8 * 8;
  float4 x0 = *(const float4*)src;
  float4 x1 = *(const float4*)(src + 4);
  float xs[8] = {x0.x, x0.y, x0.z, x0.w, x1.x, x1.y, x1.z, x1.w};
  f16x8 hv;
#pragma unroll
  for (int j = 0; j < 8; ++j) hv[j] = (_Float16)xs[j];
  *(f16x8*)((char*)H2 + (size_t)idx * 16) = hv;
}

// ---------------- LDS-free strip GEMM: wave = 32 rows x 256 cols, K=128 ----------------
// 4-wave blocks: 4 consecutive strips x same cg -> B tiles shared through L1.
// All fragment loads fully coalesced (1KB/instruction) from the tiled H2 layout.
// acc[m][ni][r] = C[row = strip*32+m*16+lr16][col = cg*256+t*64+ni*16+lq*4+r]
// A pre-scaled by SCALE2; raw-max precheck -> mask+exp2 only in triggered tiles.
__global__ __launch_bounds__(256, 4) void gemm_kernel(
    const _Float16* __restrict__ H2, const int* __restrict__ labels,
    const unsigned char* __restrict__ lab8,
    float* __restrict__ pM, float* __restrict__ pS) {
  int orig = blockIdx.x;                 // 2048 blocks
  int xcd = orig & 7, j = orig >> 3;     // dispatch round-robins XCDs (perf-only)
  int cg = xcd * 4 + (j & 3);            // [0,32): 4 col-groups pinned per XCD
  int sp = j >> 2;                       // [0,64): strip-quad
  int wave = threadIdx.x >> 6, lane = threadIdx.x & 63;
  int strip = sp * 4 + wave;             // [0,256): 32-row strip
  int lq = lane >> 4, lr16 = lane & 15;

  const uint32_t rowbase = (uint32_t)strip * 32;
  const char* Hb = (const char*)H2;
  const uint32_t laneoff = lq * 256 + lr16 * 16;   // lane's byte offset within a 1KB frag

  int lrw[2];
#pragma unroll
  for (int m = 0; m < 2; ++m)
    lrw[m] = labels[(rowbase + m * 16 + lr16) & (BSZ - 1)];

  // ---- A fragments (8 coalesced 1KB loads), pre-scaled ----
  f16x8 Areg[2][4];
#pragma unroll
  for (int m = 0; m < 2; ++m)
#pragma unroll
    for (int kb = 0; kb < 4; ++kb)
      Areg[m][kb] = *(const f16x8*)(Hb + (size_t)((rowbase >> 4) + m) * 4096 + kb * 1024 + laneoff);
#pragma unroll
  for (int m = 0; m < 2; ++m)
#pragma unroll
    for (int kb = 0; kb < 4; ++kb)
      Areg[m][kb] = Areg[m][kb] * (_Float16)SCALE2;

  const char* Bbase = Hb + (size_t)cg * 65536;     // cg*16 colblks * 4096B

#define BLOAD(T, NI, KB) \
  (*(const f16x8*)(Bbase + ((T) * 4 + (NI)) * 4096 + (KB) * 1024 + laneoff))

  f32x4 acc[2][4];
  float mxv[2] = {-3.0e38f, -3.0e38f}, sv[2] = {0.0f, 0.0f};

  f16x8 Bb[2][4];
#pragma unroll
  for (int ni = 0; ni < 4; ++ni) Bb[0][ni] = BLOAD(0, ni, 0);

#pragma unroll
  for (int t = 0; t < 4; ++t) {
#pragma unroll
    for (int m = 0; m < 2; ++m)
#pragma unroll
      for (int ni = 0; ni < 4; ++ni) acc[m][ni] = f32x4{0.f, 0.f, 0.f, 0.f};
    uint32_t labw[4];
#pragma unroll
    for (int ni = 0; ni < 4; ++ni)
      labw[ni] = *(const uint32_t*)(lab8 + cg * 256 + t * 64 + ni * 16 + lq * 4);

#pragma unroll
    for (int kb = 0; kb < 4; ++kb) {
      int cur = kb & 1;
      if (kb < 3) {
#pragma unroll
        for (int ni = 0; ni < 4; ++ni) Bb[cur ^ 1][ni] = BLOAD(t, ni, kb + 1);
      } else if (t < 3) {
#pragma unroll
        for (int ni = 0; ni < 4; ++ni) Bb[cur ^ 1][ni] = BLOAD(t + 1, ni, 0);
      }
      __builtin_amdgcn_s_setprio(1);
#pragma unroll
      for (int m = 0; m < 2; ++m)
#pragma unroll
        for (int ni = 0; ni < 4; ++ni)
          acc[m][ni] = __builtin_amdgcn_mfma_f32_16x16x32_f16(Bb[cur][ni], Areg[m][kb], acc[m][ni], 0, 0, 0);
      __builtin_amdgcn_s_setprio(0);
    }

    // ---- epilogue: raw-max precheck, then (rarely) mask + exp2 ----
#pragma unroll
    for (int m = 0; m < 2; ++m) {
      float r0 = fmaxf(fmaxf(acc[m][0][0], acc[m][0][1]), fmaxf(acc[m][0][2], acc[m][0][3]));
      float r1 = fmaxf(fmaxf(acc[m][1][0], acc[m][1][1]), fmaxf(acc[m][1][2], acc[m][1][3]));
      float r2 = fmaxf(fmaxf(acc[m][2][0], acc[m][2][1]), fmaxf(acc[m][2][2], acc[m][2][3]));
      float r3 = fmaxf(fmaxf(acc[m][3][0], acc[m][3][1]), fmaxf(acc[m][3][2], acc[m][3][3]));
      float rm = fmaxf(fmaxf(r0, r1), fmaxf(r2, r3));
      rm = fmaxf(rm, __shfl_xor(rm, 16, 64));
      rm = fmaxf(rm, __shfl_xor(rm, 32, 64));
      // raw max >= masked max (masked entries are 0, covered by the 0-clamp);
      // the tile holding the row's true masked max always satisfies this.
      if (__any(fmaxf(rm, 0.0f) > mxv[m] - SKIP_THR)) {
#pragma unroll
        for (int ni = 0; ni < 4; ++ni)
#pragma unroll
          for (int r = 0; r < 4; ++r) {
            int lc = (labw[ni] >> (8 * r)) & 255;
            acc[m][ni][r] = (lrw[m] != lc) ? acc[m][ni][r] : 0.0f;
          }
        float b0 = fmaxf(fmaxf(acc[m][0][0], acc[m][0][1]), fmaxf(acc[m][0][2], acc[m][0][3]));
        float b1 = fmaxf(fmaxf(acc[m][1][0], acc[m][1][1]), fmaxf(acc[m][1][2], acc[m][1][3]));
        float b2 = fmaxf(fmaxf(acc[m][2][0], acc[m][2][1]), fmaxf(acc[m][2][2], acc[m][2][3]));
        float b3 = fmaxf(fmaxf(acc[m][3][0], acc[m][3][1]), fmaxf(acc[m][3][2], acc[m][3][3]));
        float bm = fmaxf(fmaxf(b0, b1), fmaxf(b2, b3));
        bm = fmaxf(bm, __shfl_xor(bm, 16, 64));
        bm = fmaxf(bm, __shfl_xor(bm, 32, 64));
        float nm = fmaxf(mxv[m], bm);
        float s = 0.0f;
#pragma unroll
        for (int ni = 0; ni < 4; ++ni)
#pragma unroll
          for (int r = 0; r < 4; ++r) s += EXP2(acc[m][ni][r] - nm);
        sv[m] = sv[m] * EXP2(mxv[m] - nm) + s;   // per-lane partial, row-uniform nm
        mxv[m] = nm;
      }
    }
  }
#undef BLOAD

  // ---- cross-lq sum and write per-(row, cg) partials ----
#pragma unroll
  for (int m = 0; m < 2; ++m) {
    float s = sv[m];
    s += __shfl_xor(s, 16, 64);
    s += __shfl_xor(s, 32, 64);
    if (lane < 16) {
      pM[(size_t)cg * N_TOT + rowbase + m * 16 + lane] = mxv[m];
      pS[(size_t)cg * N_TOT + rowbase + m * 16 + lane] = s;
    }
  }
}

// ---------------- combine 32 chunk-partials per row, partial-sum S per block ----------------
__global__ __launch_bounds__(256) void rowred_kernel(const float* __restrict__ pM,
                                                     const float* __restrict__ pS,
                                                     float* __restrict__ blockS) {
  int row = blockIdx.x * 256 + threadIdx.x;   // 32 blocks x 256 = 8192 rows
  float M = -3.0e38f;
#pragma unroll
  for (int c = 0; c < NCH; ++c) M = fmaxf(M, pM[(size_t)c * N_TOT + row]);
  float s = 0.0f;
#pragma unroll
  for (int c = 0; c < NCH; ++c)
    s += pS[(size_t)c * N_TOT + row] * EXP2(pM[(size_t)c * N_TOT + row] - M);
  __shared__ float red[256];
  red[threadIdx.x] = s;
  __syncthreads();
  for (int st = 128; st > 0; st >>= 1) {
    if (threadIdx.x < st) red[threadIdx.x] += red[threadIdx.x + st];
    __syncthreads();
  }
  if (threadIdx.x == 0) blockS[blockIdx.x] = red[0];
}

// ---------------- final scalar: S, N, validity -> loss ----------------
__global__ void final_kernel(const float* __restrict__ blockS, const int* __restrict__ cnt,
                             float* __restrict__ out) {
  int lane = threadIdx.x;              // 1 wave
  float s = (lane < 32) ? blockS[lane] : 0.0f;
#pragma unroll
  for (int off = 1; off < 64; off <<= 1) s += __shfl_xor(s, off, 64);
  if (lane == 0) {
    double Stot = (double)s;
    long long sumsq = 0;
    int nval = 0;
    for (int c = 0; c < 128; ++c) {
      long long cc = cnt[c];
      sumsq += cc * cc;
      if (cc > 0 && cc < BSZ) nval += 2 * (int)cc;   // valid rows iff not all labels equal
    }
    double Nd = (double)N_TOT * (double)N_TOT - 4.0 * (double)sumsq;
    float loss;
    if (Nd <= 0.0 || nval == 0) {
      loss = logf(1e-6f);              // all_zero branch: xv stays 0 -> log(eps)
    } else {
      float x = (float)(Stot / Nd);
      loss = ((float)nval * logf(x + 1e-6f) +
              (float)(N_TOT - nval) * logf(1e-6f)) / (float)N_TOT;
    }
    out[0] = loss;
  }
}

extern "C" void kernel_launch(void* const* d_in, const int* in_sizes, int n_in,
                              void* d_out, int out_size, void* d_ws, size_t ws_size,
                              hipStream_t stream) {
  const float* feat = (const float*)d_in[0];
  const int* labels = (const int*)d_in[1];
  float* out = (float*)d_out;

  char* ws = (char*)d_ws;
  _Float16* H2        = (_Float16*)(ws);                 // 8192*128*2 = 2,097,152 (tiled layout)
  unsigned char* lab8 = (unsigned char*)(ws + 2097152);  // 8,192
  float* pM           = (float*)(ws + 2105344);          // 32*8192*4 = 1,048,576
  float* pS           = (float*)(ws + 3153920);          // 1,048,576
  int* cnt            = (int*)(ws + 4202496);            // 512
  float* blockS       = (float*)(ws + 4203008);          // 128

  prep_kernel<<<513, 256, 0, stream>>>(feat, labels, H2, lab8, cnt);
  gemm_kernel<<<2048, 256, 0, stream>>>(H2, labels, lab8, pM, pS);
  rowred_kernel<<<32, 256, 0, stream>>>(pM, pS, blockS);
  final_kernel<<<1, 64, 0, stream>>>(blockS, cnt, out);
}